// Round 5
// baseline (357.606 us; speedup 1.0000x reference)
//
#include <hip/hip_runtime.h>
#include <stdint.h>
#include <stddef.h>

// AttentiveTransformer: B=65536, D_IN=128, F=512, fp32
#define NROWS 65536
#define DK 128
#define NF 512
#define LDS_H 524               // halves per LDS row (stride): keeps both LDS phases <=2-way
#define BN_EPS 1e-3f

typedef __attribute__((ext_vector_type(8))) short short8;     // 8 x bf16
typedef __attribute__((ext_vector_type(8))) _Float16 half8;   // 8 x fp16
typedef __attribute__((ext_vector_type(4))) float f32x4;

__device__ __forceinline__ unsigned short f2bf(float f) {
  unsigned int u = __builtin_bit_cast(unsigned int, f);
  u += 0x7fffu + ((u >> 16) & 1u);     // RNE
  return (unsigned short)(u >> 16);
}
__device__ __forceinline__ float bf2f(unsigned short h) {
  unsigned int u = ((unsigned int)h) << 16;
  return __builtin_bit_cast(float, u);
}

// ---------------------------------------------------------------------------
// Prep: fold BN scale alpha into W, transpose to [512][128], split bf16 hi/lo.
// ---------------------------------------------------------------------------
__global__ void prep_kernel(const float* __restrict__ W,
                            const float* __restrict__ bias,
                            const float* __restrict__ gamma,
                            const float* __restrict__ beta,
                            const float* __restrict__ mean,
                            const float* __restrict__ var,
                            unsigned short* __restrict__ wt_hi,
                            unsigned short* __restrict__ wt_lo,
                            float* __restrict__ delta) {
  int bid = blockIdx.x, tid = threadIdx.x;
  if (bid < 256) {
    int idx = bid * 256 + tid;        // over [512][128]
    int f = idx >> 7, d = idx & 127;
    float a = gamma[f] * rsqrtf(var[f] + BN_EPS);
    float wv = W[(size_t)d * NF + f] * a;   // alpha folded into weights
    unsigned short wh = f2bf(wv);
    wt_hi[idx] = wh;                  // wt[f][d], contiguous stores
    wt_lo[idx] = f2bf(wv - bf2f(wh));
  } else {
#pragma unroll
    for (int i = 0; i < 2; ++i) {
      int f = tid + i * 256;
      float a = gamma[f] * rsqrtf(var[f] + BN_EPS);
      delta[f] = (bias[f] - mean[f]) * a + beta[f];
    }
  }
}

// ---------------------------------------------------------------------------
// Fused kernel: 512 threads (8 waves), 32 rows per block.
// KEY R5 change: prior loads are issued at the TOP of the kernel (pinned by
// sched_barrier), so their ~900-cyc HBM latency is covered by the entire
// A-convert + MFMA phase instead of being drained cold at the pre-s_barrier
// vmcnt(0) (the compiler always fully drains vmem before s_barrier - m97).
//  Phase 1: wave w computes cols [64w,64w+64) x 32 rows, split-bf16 MFMA
//           (3 products ~ fp32 accuracy), +delta, fp16 z -> LDS (stride 524).
//  Phase 2: 16-lane group owns one row; Michelot fixed-point sparsemax;
//           coalesced float4 out stores.
// ---------------------------------------------------------------------------
__global__ __launch_bounds__(512, 4) void fused_kernel(
    const float* __restrict__ inp,            // [65536][128]
    const float* __restrict__ prior,          // [65536][512]
    const unsigned short* __restrict__ wt_hi, // [512][128] bf16 hi (alpha-folded)
    const unsigned short* __restrict__ wt_lo, // [512][128] bf16 lo
    const float* __restrict__ delta,          // [512]
    float* __restrict__ out) {                // [65536][512]
  __shared__ _Float16 zsh[32 * LDS_H];        // 33536 B

  const int tid = threadIdx.x;
  const int w = tid >> 6;        // wave 0..7
  const int l = tid & 63;
  const int q = l >> 4;          // quad 0..3
  const int li = l & 15;
  const int r0 = blockIdx.x * 32;
  const int n0 = w * 64;         // this wave's column slice

  // ---- Prior loads FIRST: latency hides behind the whole GEMM phase ----
  const int g = tid >> 4;                     // 0..31: this thread's row (phase 2)
  const int li2 = tid & 15;
  const size_t grow = (size_t)(r0 + g);
  const float* prow = prior + grow * NF + li2 * 8;
  f32x4 pv[8];
#pragma unroll
  for (int j = 0; j < 4; ++j) {
    pv[2 * j]     = *(const f32x4*)(prow + 128 * j);
    pv[2 * j + 1] = *(const f32x4*)(prow + 128 * j + 4);
  }
  __builtin_amdgcn_sched_barrier(0);          // pin: pv loads must issue here

  // ---- Phase 1a: load + split-convert A fragments (2 m-tiles, 32 rows) ----
  short8 ah[2][4], al[2][4];
#pragma unroll
  for (int m = 0; m < 2; ++m) {
    const float* arow = inp + (size_t)(r0 + m * 16 + li) * DK + q * 8;
#pragma unroll
    for (int kk = 0; kk < 4; ++kk) {
      float4 v0 = *(const float4*)(arow + kk * 32);
      float4 v1 = *(const float4*)(arow + kk * 32 + 4);
      float av[8] = {v0.x, v0.y, v0.z, v0.w, v1.x, v1.y, v1.z, v1.w};
      short8 h, lo;
#pragma unroll
      for (int j = 0; j < 8; ++j) {
        unsigned short hb = f2bf(av[j]);
        h[j] = (short)hb;
        lo[j] = (short)f2bf(av[j] - bf2f(hb));
      }
      ah[m][kk] = h;
      al[m][kk] = lo;
    }
  }

  // ---- delta preload (tiny, before GEMM so epilogue doesn't stall) ----
  float dv[4];
#pragma unroll
  for (int t = 0; t < 4; ++t) dv[t] = delta[n0 + t * 16 + li];

  // ---- Phase 1b: MFMA, 3-product split-bf16, 4 col-tiles ----
  f32x4 acc[2][4];
#pragma unroll
  for (int m = 0; m < 2; ++m)
#pragma unroll
    for (int t = 0; t < 4; ++t) acc[m][t] = (f32x4){0.f, 0.f, 0.f, 0.f};

#pragma unroll
  for (int t = 0; t < 4; ++t) {
    const unsigned short* wbh = wt_hi + (size_t)(n0 + t * 16 + li) * DK + q * 8;
    const unsigned short* wbl = wt_lo + (size_t)(n0 + t * 16 + li) * DK + q * 8;
    // group all 8 tile loads so the compiler pipelines them ahead of the MFMAs
    short8 WH0 = *(const short8*)(wbh);
    short8 WL0 = *(const short8*)(wbl);
    short8 WH1 = *(const short8*)(wbh + 32);
    short8 WL1 = *(const short8*)(wbl + 32);
    short8 WH2 = *(const short8*)(wbh + 64);
    short8 WL2 = *(const short8*)(wbl + 64);
    short8 WH3 = *(const short8*)(wbh + 96);
    short8 WL3 = *(const short8*)(wbl + 96);
    short8 WH[4] = {WH0, WH1, WH2, WH3};
    short8 WL[4] = {WL0, WL1, WL2, WL3};
#pragma unroll
    for (int kk = 0; kk < 4; ++kk) {
#pragma unroll
      for (int m = 0; m < 2; ++m) {
        acc[m][t] = __builtin_amdgcn_mfma_f32_16x16x32_bf16(ah[m][kk], WH[kk], acc[m][t], 0, 0, 0);
        acc[m][t] = __builtin_amdgcn_mfma_f32_16x16x32_bf16(al[m][kk], WH[kk], acc[m][t], 0, 0, 0);
        acc[m][t] = __builtin_amdgcn_mfma_f32_16x16x32_bf16(ah[m][kk], WL[kk], acc[m][t], 0, 0, 0);
      }
    }
  }

  // ---- Phase 1c: +delta, fp16 convert, write z to LDS ----
#pragma unroll
  for (int t = 0; t < 4; ++t) {
    int col = n0 + t * 16 + li;
#pragma unroll
    for (int m = 0; m < 2; ++m) {
#pragma unroll
      for (int r = 0; r < 4; ++r) {
        zsh[(m * 16 + q * 4 + r) * LDS_H + col] = (_Float16)(acc[m][t][r] + dv[t]);
      }
    }
  }

  __syncthreads();

  // ---- Phase 2: per-row prior-scaled sparsemax (16-lane group = row) ----
  // lane's cols: li2*8 + 128*j + c, j=0..3, c=0..7  (pv already in regs)
  float z[32];
#pragma unroll
  for (int j = 0; j < 4; ++j) {
    half8 hv = *(const half8*)&zsh[g * LDS_H + li2 * 8 + 128 * j];
#pragma unroll
    for (int c = 0; c < 8; ++c) {
      z[8 * j + c] = (float)hv[c] * pv[2 * j + (c >> 2)][c & 3];
    }
  }

  float mx = z[0];
#pragma unroll
  for (int j = 1; j < 32; ++j) mx = fmaxf(mx, z[j]);
#pragma unroll
  for (int off = 1; off <= 8; off <<= 1) mx = fmaxf(mx, __shfl_xor(mx, off, 64));

  // Michelot fixed-point: tau <- (sum_S - 1)/|S|, S = {z > tau}
  float tau = mx - 1.0f;
  float cprev = -1.0f;
  for (int it = 0; it < 40; ++it) {
    float s = 0.0f, c = 0.0f;
#pragma unroll
    for (int j = 0; j < 32; ++j) {
      bool in = z[j] > tau;
      s += in ? z[j] : 0.0f;
      c += in ? 1.0f : 0.0f;
    }
#pragma unroll
    for (int off = 1; off <= 8; off <<= 1) {
      s += __shfl_xor(s, off, 64);
      c += __shfl_xor(c, off, 64);
    }
    tau = (s - 1.0f) / c;
    if (__all(c == cprev)) break;
    cprev = c;
  }

  float* orow = out + grow * NF + li2 * 8;
#pragma unroll
  for (int j = 0; j < 4; ++j) {
    f32x4 ov0, ov1;
#pragma unroll
    for (int r = 0; r < 4; ++r) {
      ov0[r] = fmaxf(z[8 * j + r] - tau, 0.0f);
      ov1[r] = fmaxf(z[8 * j + 4 + r] - tau, 0.0f);
    }
    *(f32x4*)(orow + 128 * j) = ov0;
    *(f32x4*)(orow + 128 * j + 4) = ov1;
  }
}

// ---------------------------------------------------------------------------
extern "C" void kernel_launch(void* const* d_in, const int* in_sizes, int n_in,
                              void* d_out, int out_size, void* d_ws, size_t ws_size,
                              hipStream_t stream) {
  const float* inp   = (const float*)d_in[0];   // [65536][128]
  const float* prior = (const float*)d_in[1];   // [65536][512]
  const float* W     = (const float*)d_in[2];   // [128][512]
  const float* bias  = (const float*)d_in[3];   // [512]
  const float* gamma = (const float*)d_in[4];
  const float* beta  = (const float*)d_in[5];
  const float* mean  = (const float*)d_in[6];
  const float* var   = (const float*)d_in[7];
  float* out = (float*)d_out;

  // workspace carve: 131072 + 131072 + 2048 bytes
  unsigned short* wt_hi = (unsigned short*)d_ws;
  unsigned short* wt_lo = wt_hi + (size_t)NF * DK;
  float* delta = (float*)(wt_lo + (size_t)NF * DK);

  prep_kernel<<<257, 256, 0, stream>>>(W, bias, gamma, beta, mean, var,
                                       wt_hi, wt_lo, delta);
  fused_kernel<<<NROWS / 32, 512, 0, stream>>>(inp, prior, wt_hi, wt_lo,
                                               delta, out);
}